// Round 5
// baseline (60.303 us; speedup 1.0000x reference)
//
#include <hip/hip_runtime.h>
#include <math.h>

#define B_    256
#define K_    5
#define N_    4096
#define NPAIR (B_ * K_)     // 1280
#define NMOM  17

// ---------------------------------------------------------------------------
// Fully fused kernel (f32 eigensolve):
//   phase 1: per-(b,k) moment reduction over N=4096 points (memory-bound).
//            Block index idx = k*256 + b so all K=5 blocks sharing target
//            slice b land on the same XCD (idx%8 == b%8) -> target re-reads
//            are L2-local; unique HBM traffic = 75.5 MB.
//   phase 2: lane 0 computes the 3x3 "SVD" (eigendecomp of H^T H) and the
//            pair's rmsd in f32 (~1k-cycle chain; the f64 version was ~20k
//            cycles of OCML emulation and serialized 5-deep per CU in R4),
//            reproducing the reference's buggy R = Vh diag(1,1,d) U^T via
//            tr(H R) = S0*M00+S1*M11+d*S2*M22, M = Vh*Vh, d = sign(det H).
//   phase 3: the last block to finish reduces all 1280 rmsds (min over k,
//            mean over b) in a fixed order -> deterministic scalar output.
// ---------------------------------------------------------------------------
__device__ inline void cross3f(const float* a, const float* b, float* c) {
  c[0] = a[1] * b[2] - a[2] * b[1];
  c[1] = a[2] * b[0] - a[0] * b[2];
  c[2] = a[0] * b[1] - a[1] * b[0];
}
__device__ inline float dot3f(const float* a, const float* b) {
  return a[0] * b[0] + a[1] * b[1] + a[2] * b[2];
}
__device__ inline void fixsign3f(float* v) {
  const float a0 = fabsf(v[0]), a1 = fabsf(v[1]), a2 = fabsf(v[2]);
  const int i = (a0 >= a1 && a0 >= a2) ? 0 : ((a1 >= a2) ? 1 : 2);
  if (v[i] < 0.f) { v[0] = -v[0]; v[1] = -v[1]; v[2] = -v[2]; }
}
__device__ inline void eigvec3f(const float A[3][3], float lam, float* v) {
  const float r0[3] = {A[0][0] - lam, A[0][1], A[0][2]};
  const float r1[3] = {A[1][0], A[1][1] - lam, A[1][2]};
  const float r2[3] = {A[2][0], A[2][1], A[2][2] - lam};
  float c01[3], c02[3], c12[3];
  cross3f(r0, r1, c01); cross3f(r0, r2, c02); cross3f(r1, r2, c12);
  const float n01 = dot3f(c01, c01), n02 = dot3f(c02, c02), n12 = dot3f(c12, c12);
  const float* best = c01; float nb = n01;
  if (n02 > nb) { best = c02; nb = n02; }
  if (n12 > nb) { best = c12; nb = n12; }
  if (nb < 1e-30f) { v[0] = 1.f; v[1] = 0.f; v[2] = 0.f; return; }
  const float inv = 1.f / sqrtf(nb);
  v[0] = best[0] * inv; v[1] = best[1] * inv; v[2] = best[2] * inv;
}

__device__ inline float svd_rmsd(const float* m) {
  const float invN = 1.f / (float)N_;
  const float sP[3] = {m[0], m[1], m[2]};
  const float sQ[3] = {m[3], m[4], m[5]};
  float H[3][3];
#pragma unroll
  for (int i = 0; i < 3; ++i)
#pragma unroll
    for (int j = 0; j < 3; ++j)
      H[i][j] = m[8 + 3 * i + j] - sP[i] * sQ[j] * invN;

  const float Sp = m[6] - dot3f(sP, sP) * invN;
  const float Sq = m[7] - dot3f(sQ, sQ) * invN;

  // A = H^T H (symmetric PSD)
  float A[3][3];
#pragma unroll
  for (int i = 0; i < 3; ++i)
#pragma unroll
    for (int j = 0; j < 3; ++j)
      A[i][j] = H[0][i] * H[0][j] + H[1][i] * H[1][j] + H[2][i] * H[2][j];

  float lam[3];
  float V[3][3];  // columns = eigenvectors
  const float q = (A[0][0] + A[1][1] + A[2][2]) * (1.f / 3.f);
  const float p1 = A[0][1] * A[0][1] + A[0][2] * A[0][2] + A[1][2] * A[1][2];
  const float p2 = (A[0][0] - q) * (A[0][0] - q) +
                   (A[1][1] - q) * (A[1][1] - q) +
                   (A[2][2] - q) * (A[2][2] - q) + 2.f * p1;
  if (p2 < 1e-20f) {
    lam[0] = lam[1] = lam[2] = q;
#pragma unroll
    for (int i = 0; i < 3; ++i)
#pragma unroll
      for (int j = 0; j < 3; ++j) V[i][j] = (i == j) ? 1.f : 0.f;
  } else {
    const float p = sqrtf(p2 * (1.f / 6.f));
    const float invp = 1.f / p;
    float Bm[3][3];
#pragma unroll
    for (int i = 0; i < 3; ++i)
#pragma unroll
      for (int j = 0; j < 3; ++j)
        Bm[i][j] = (A[i][j] - ((i == j) ? q : 0.f)) * invp;
    const float detB =
        Bm[0][0] * (Bm[1][1] * Bm[2][2] - Bm[1][2] * Bm[2][1]) -
        Bm[0][1] * (Bm[1][0] * Bm[2][2] - Bm[1][2] * Bm[2][0]) +
        Bm[0][2] * (Bm[1][0] * Bm[2][1] - Bm[1][1] * Bm[2][0]);
    float r = detB * 0.5f;
    r = fminf(1.f, fmaxf(-1.f, r));
    const float phi = acosf(r) * (1.f / 3.f);
    lam[0] = q + 2.f * p * cosf(phi);
    lam[2] = q + 2.f * p * cosf(phi + 2.0943951023931953f);  // +2pi/3
    lam[1] = 3.f * q - lam[0] - lam[2];

    float v1[3], v2[3], v3[3];
    eigvec3f(A, lam[0], v1);
    eigvec3f(A, lam[1], v2);
    // orthogonalize v2 against v1
    const float d12 = dot3f(v1, v2);
    v2[0] -= d12 * v1[0]; v2[1] -= d12 * v1[1]; v2[2] -= d12 * v1[2];
    float n2 = dot3f(v2, v2);
    if (n2 < 1e-12f) {
      const float a0 = fabsf(v1[0]), a1f = fabsf(v1[1]), a2f = fabsf(v1[2]);
      int ax = (a0 <= a1f && a0 <= a2f) ? 0 : ((a1f <= a2f) ? 1 : 2);
      float e[3] = {0.f, 0.f, 0.f};
      e[ax] = 1.f;
      const float de = dot3f(v1, e);
      v2[0] = e[0] - de * v1[0]; v2[1] = e[1] - de * v1[1]; v2[2] = e[2] - de * v1[2];
      n2 = dot3f(v2, v2);
    }
    const float invn2 = 1.f / sqrtf(n2);
    v2[0] *= invn2; v2[1] *= invn2; v2[2] *= invn2;

    fixsign3f(v1);
    fixsign3f(v2);
    cross3f(v1, v2, v3);
#pragma unroll
    for (int i = 0; i < 3; ++i) { V[i][0] = v1[i]; V[i][1] = v2[i]; V[i][2] = v3[i]; }
  }

  const float S0 = sqrtf(fmaxf(lam[0], 0.f));
  const float S1 = sqrtf(fmaxf(lam[1], 0.f));
  const float S2 = sqrtf(fmaxf(lam[2], 0.f));

  const float detH =
      H[0][0] * (H[1][1] * H[2][2] - H[1][2] * H[2][1]) -
      H[0][1] * (H[1][0] * H[2][2] - H[1][2] * H[2][0]) +
      H[0][2] * (H[1][0] * H[2][1] - H[1][1] * H[2][0]);
  const float dsg = (detH >= 0.f) ? 1.f : -1.f;

  // M = Vh*Vh (Vh = V^T): M_ii = sum_k V[k][i] * V[i][k]
  const float M00 = V[0][0] * V[0][0] + V[1][0] * V[0][1] + V[2][0] * V[0][2];
  const float M11 = V[0][1] * V[1][0] + V[1][1] * V[1][1] + V[2][1] * V[1][2];
  const float M22 = V[0][2] * V[2][0] + V[1][2] * V[2][1] + V[2][2] * V[2][2];

  const float T = S0 * M00 + S1 * M11 + dsg * S2 * M22;
  const float mse = (Sp + Sq - 2.f * T) * (1.f / (3.f * (float)N_));
  return sqrtf(mse + 1e-8f);
}

__global__ __launch_bounds__(256) void kabsch_fused(
    const float* __restrict__ preds, const float* __restrict__ target,
    unsigned int* __restrict__ cnt, float* __restrict__ rm,
    float* __restrict__ out) {
  const int idx = blockIdx.x;         // 0..1279, idx = k*256 + b
  const int b = idx & 255;
  const int k = idx >> 8;
  const int pair_orig = b * K_ + k;   // preds memory order is [B,K,N,3]
  const int tid = threadIdx.x;

  const float4* __restrict__ P4 =
      reinterpret_cast<const float4*>(preds) + (size_t)pair_orig * (N_ * 3 / 4);
  const float4* __restrict__ Q4 =
      reinterpret_cast<const float4*>(target) + (size_t)b * (N_ * 3 / 4);

  float acc[NMOM];
#pragma unroll
  for (int i = 0; i < NMOM; ++i) acc[i] = 0.f;

  // 4096 points = 1024 chunks of 4 points (3 float4 each); 256 threads x 4 chunks
#pragma unroll
  for (int j = 0; j < 4; ++j) {
    const int c = tid + j * 256;
    const float4 a0 = P4[3 * c + 0], a1 = P4[3 * c + 1], a2 = P4[3 * c + 2];
    const float4 b0 = Q4[3 * c + 0], b1 = Q4[3 * c + 1], b2 = Q4[3 * c + 2];
    const float p[4][3] = {{a0.x, a0.y, a0.z},
                           {a0.w, a1.x, a1.y},
                           {a1.z, a1.w, a2.x},
                           {a2.y, a2.z, a2.w}};
    const float q[4][3] = {{b0.x, b0.y, b0.z},
                           {b0.w, b1.x, b1.y},
                           {b1.z, b1.w, b2.x},
                           {b2.y, b2.z, b2.w}};
#pragma unroll
    for (int m = 0; m < 4; ++m) {
      const float px = p[m][0], py = p[m][1], pz = p[m][2];
      const float qx = q[m][0], qy = q[m][1], qz = q[m][2];
      acc[0] += px; acc[1] += py; acc[2] += pz;
      acc[3] += qx; acc[4] += qy; acc[5] += qz;
      acc[6] = fmaf(px, px, fmaf(py, py, fmaf(pz, pz, acc[6])));
      acc[7] = fmaf(qx, qx, fmaf(qy, qy, fmaf(qz, qz, acc[7])));
      acc[8]  = fmaf(px, qx, acc[8]);
      acc[9]  = fmaf(px, qy, acc[9]);
      acc[10] = fmaf(px, qz, acc[10]);
      acc[11] = fmaf(py, qx, acc[11]);
      acc[12] = fmaf(py, qy, acc[12]);
      acc[13] = fmaf(py, qz, acc[13]);
      acc[14] = fmaf(pz, qx, acc[14]);
      acc[15] = fmaf(pz, qy, acc[15]);
      acc[16] = fmaf(pz, qz, acc[16]);
    }
  }

  // wave64 butterfly reduce, then cross-wave via LDS
#pragma unroll
  for (int off = 32; off > 0; off >>= 1) {
#pragma unroll
    for (int i = 0; i < NMOM; ++i) acc[i] += __shfl_down(acc[i], off, 64);
  }

  __shared__ float red[4][NMOM];
  __shared__ unsigned int s_done;
  const int lane = tid & 63, wid = tid >> 6;
  if (lane == 0) {
#pragma unroll
    for (int i = 0; i < NMOM; ++i) red[wid][i] = acc[i];
  }
  __syncthreads();

  // --- phase 2: one lane does the 3x3 eigensolve + rmsd, publishes it ---
  if (tid == 0) {
    float m[NMOM];
#pragma unroll
    for (int i = 0; i < NMOM; ++i)
      m[i] = red[0][i] + red[1][i] + red[2][i] + red[3][i];
    const float r = svd_rmsd(m);
    __hip_atomic_store(rm + idx, r, __ATOMIC_RELAXED, __HIP_MEMORY_SCOPE_AGENT);
    const unsigned int old = __hip_atomic_fetch_add(
        cnt, 1u, __ATOMIC_ACQ_REL, __HIP_MEMORY_SCOPE_AGENT);
    s_done = (old == (unsigned int)(NPAIR - 1)) ? 1u : 0u;
  }
  __syncthreads();

  // --- phase 3: last block reduces min-over-k, mean-over-b ---
  if (s_done) {
    __threadfence();  // acquire for non-tid0 threads
    const int bb = tid;  // 256 threads == B_
    float mn = __hip_atomic_load(rm + bb, __ATOMIC_RELAXED,
                                 __HIP_MEMORY_SCOPE_AGENT);
#pragma unroll
    for (int kk = 1; kk < K_; ++kk) {
      const float v = __hip_atomic_load(rm + kk * 256 + bb, __ATOMIC_RELAXED,
                                        __HIP_MEMORY_SCOPE_AGENT);
      mn = fminf(mn, v);
    }
#pragma unroll
    for (int off = 32; off > 0; off >>= 1) mn += __shfl_down(mn, off, 64);
    __shared__ float s[4];
    if ((tid & 63) == 0) s[tid >> 6] = mn;
    __syncthreads();
    if (tid == 0) out[0] = (s[0] + s[1] + s[2] + s[3]) * (1.0f / 256.0f);
  }
}

extern "C" void kernel_launch(void* const* d_in, const int* in_sizes, int n_in,
                              void* d_out, int out_size, void* d_ws, size_t ws_size,
                              hipStream_t stream) {
  const float* preds = (const float*)d_in[0];
  const float* target = (const float*)d_in[1];
  float* out = (float*)d_out;
  unsigned int* cnt = (unsigned int*)d_ws;          // 1 uint at offset 0
  float* rm = (float*)d_ws + 4;                      // NPAIR floats at +16B

  // Counter must be 0 at kernel start (ws is poisoned 0xAA once, never
  // re-poisoned; kernel leaves it at NPAIR). Graph-capturable memset node.
  hipMemsetAsync(d_ws, 0, 4, stream);
  hipLaunchKernelGGL(kabsch_fused, dim3(NPAIR), dim3(256), 0, stream,
                     preds, target, cnt, rm, out);
}

// Round 6
// 36.508 us; speedup vs baseline: 1.6518x; 1.6518x over previous
//
#include <hip/hip_runtime.h>
#include <math.h>

#define B_    256
#define K_    5
#define N_    4096
#define NPAIR (B_ * K_)     // 1280
#define NMOM  17

// ---------------------------------------------------------------------------
// Fully fused kernel (f32 eigensolve, relaxed-atomic last-block sync):
//   phase 1: per-(b,k) moment reduction over N=4096 points (memory-bound).
//            Block index idx = k*256 + b so all K=5 blocks sharing target
//            slice b land on the same XCD (idx%8 == b%8) -> target re-reads
//            are L2-local; unique HBM traffic = 75.5 MB.
//   phase 2: lane 0 computes the 3x3 "SVD" (eigendecomp of H^T H) and the
//            pair's rmsd in f32, reproducing the reference's buggy
//            R = Vh diag(1,1,d) U^T via tr(H R) = S0*M00+S1*M11+d*S2*M22,
//            M = Vh*Vh, d = sign(det H). Publishes rmsd with an sc1-coherent
//            relaxed atomic store, waits vmcnt(0) (store ack'd at coherence
//            point), then bumps the counter with a RELAXED fetch_add.
//            NOTE: R4/R5 used ACQ_REL here -> buffer_wbl2+buffer_inv per
//            block (1280 L2 flush/invalidate pairs) destroyed phase-1 L2
//            locality and cost ~50 us. Relaxed + explicit vmcnt is enough:
//            rm stores/loads are cache-bypassing (agent-scope atomics).
//   phase 3: the last block to finish reduces all 1280 rmsds (min over k,
//            mean over b) in a fixed order -> deterministic scalar output.
// ---------------------------------------------------------------------------
__device__ inline void cross3f(const float* a, const float* b, float* c) {
  c[0] = a[1] * b[2] - a[2] * b[1];
  c[1] = a[2] * b[0] - a[0] * b[2];
  c[2] = a[0] * b[1] - a[1] * b[0];
}
__device__ inline float dot3f(const float* a, const float* b) {
  return a[0] * b[0] + a[1] * b[1] + a[2] * b[2];
}
__device__ inline void fixsign3f(float* v) {
  const float a0 = fabsf(v[0]), a1 = fabsf(v[1]), a2 = fabsf(v[2]);
  const int i = (a0 >= a1 && a0 >= a2) ? 0 : ((a1 >= a2) ? 1 : 2);
  if (v[i] < 0.f) { v[0] = -v[0]; v[1] = -v[1]; v[2] = -v[2]; }
}
__device__ inline void eigvec3f(const float A[3][3], float lam, float* v) {
  const float r0[3] = {A[0][0] - lam, A[0][1], A[0][2]};
  const float r1[3] = {A[1][0], A[1][1] - lam, A[1][2]};
  const float r2[3] = {A[2][0], A[2][1], A[2][2] - lam};
  float c01[3], c02[3], c12[3];
  cross3f(r0, r1, c01); cross3f(r0, r2, c02); cross3f(r1, r2, c12);
  const float n01 = dot3f(c01, c01), n02 = dot3f(c02, c02), n12 = dot3f(c12, c12);
  const float* best = c01; float nb = n01;
  if (n02 > nb) { best = c02; nb = n02; }
  if (n12 > nb) { best = c12; nb = n12; }
  if (nb < 1e-30f) { v[0] = 1.f; v[1] = 0.f; v[2] = 0.f; return; }
  const float inv = 1.f / sqrtf(nb);
  v[0] = best[0] * inv; v[1] = best[1] * inv; v[2] = best[2] * inv;
}

__device__ inline float svd_rmsd(const float* m) {
  const float invN = 1.f / (float)N_;
  const float sP[3] = {m[0], m[1], m[2]};
  const float sQ[3] = {m[3], m[4], m[5]};
  float H[3][3];
#pragma unroll
  for (int i = 0; i < 3; ++i)
#pragma unroll
    for (int j = 0; j < 3; ++j)
      H[i][j] = m[8 + 3 * i + j] - sP[i] * sQ[j] * invN;

  const float Sp = m[6] - dot3f(sP, sP) * invN;
  const float Sq = m[7] - dot3f(sQ, sQ) * invN;

  // A = H^T H (symmetric PSD)
  float A[3][3];
#pragma unroll
  for (int i = 0; i < 3; ++i)
#pragma unroll
    for (int j = 0; j < 3; ++j)
      A[i][j] = H[0][i] * H[0][j] + H[1][i] * H[1][j] + H[2][i] * H[2][j];

  float lam[3];
  float V[3][3];  // columns = eigenvectors
  const float q = (A[0][0] + A[1][1] + A[2][2]) * (1.f / 3.f);
  const float p1 = A[0][1] * A[0][1] + A[0][2] * A[0][2] + A[1][2] * A[1][2];
  const float p2 = (A[0][0] - q) * (A[0][0] - q) +
                   (A[1][1] - q) * (A[1][1] - q) +
                   (A[2][2] - q) * (A[2][2] - q) + 2.f * p1;
  if (p2 < 1e-20f) {
    lam[0] = lam[1] = lam[2] = q;
#pragma unroll
    for (int i = 0; i < 3; ++i)
#pragma unroll
      for (int j = 0; j < 3; ++j) V[i][j] = (i == j) ? 1.f : 0.f;
  } else {
    const float p = sqrtf(p2 * (1.f / 6.f));
    const float invp = 1.f / p;
    float Bm[3][3];
#pragma unroll
    for (int i = 0; i < 3; ++i)
#pragma unroll
      for (int j = 0; j < 3; ++j)
        Bm[i][j] = (A[i][j] - ((i == j) ? q : 0.f)) * invp;
    const float detB =
        Bm[0][0] * (Bm[1][1] * Bm[2][2] - Bm[1][2] * Bm[2][1]) -
        Bm[0][1] * (Bm[1][0] * Bm[2][2] - Bm[1][2] * Bm[2][0]) +
        Bm[0][2] * (Bm[1][0] * Bm[2][1] - Bm[1][1] * Bm[2][0]);
    float r = detB * 0.5f;
    r = fminf(1.f, fmaxf(-1.f, r));
    const float phi = acosf(r) * (1.f / 3.f);
    lam[0] = q + 2.f * p * cosf(phi);
    lam[2] = q + 2.f * p * cosf(phi + 2.0943951023931953f);  // +2pi/3
    lam[1] = 3.f * q - lam[0] - lam[2];

    float v1[3], v2[3], v3[3];
    eigvec3f(A, lam[0], v1);
    eigvec3f(A, lam[1], v2);
    // orthogonalize v2 against v1
    const float d12 = dot3f(v1, v2);
    v2[0] -= d12 * v1[0]; v2[1] -= d12 * v1[1]; v2[2] -= d12 * v1[2];
    float n2 = dot3f(v2, v2);
    if (n2 < 1e-12f) {
      const float a0 = fabsf(v1[0]), a1f = fabsf(v1[1]), a2f = fabsf(v1[2]);
      int ax = (a0 <= a1f && a0 <= a2f) ? 0 : ((a1f <= a2f) ? 1 : 2);
      float e[3] = {0.f, 0.f, 0.f};
      e[ax] = 1.f;
      const float de = dot3f(v1, e);
      v2[0] = e[0] - de * v1[0]; v2[1] = e[1] - de * v1[1]; v2[2] = e[2] - de * v1[2];
      n2 = dot3f(v2, v2);
    }
    const float invn2 = 1.f / sqrtf(n2);
    v2[0] *= invn2; v2[1] *= invn2; v2[2] *= invn2;

    fixsign3f(v1);
    fixsign3f(v2);
    cross3f(v1, v2, v3);
#pragma unroll
    for (int i = 0; i < 3; ++i) { V[i][0] = v1[i]; V[i][1] = v2[i]; V[i][2] = v3[i]; }
  }

  const float S0 = sqrtf(fmaxf(lam[0], 0.f));
  const float S1 = sqrtf(fmaxf(lam[1], 0.f));
  const float S2 = sqrtf(fmaxf(lam[2], 0.f));

  const float detH =
      H[0][0] * (H[1][1] * H[2][2] - H[1][2] * H[2][1]) -
      H[0][1] * (H[1][0] * H[2][2] - H[1][2] * H[2][0]) +
      H[0][2] * (H[1][0] * H[2][1] - H[1][1] * H[2][0]);
  const float dsg = (detH >= 0.f) ? 1.f : -1.f;

  // M = Vh*Vh (Vh = V^T): M_ii = sum_k V[k][i] * V[i][k]
  const float M00 = V[0][0] * V[0][0] + V[1][0] * V[0][1] + V[2][0] * V[0][2];
  const float M11 = V[0][1] * V[1][0] + V[1][1] * V[1][1] + V[2][1] * V[1][2];
  const float M22 = V[0][2] * V[2][0] + V[1][2] * V[2][1] + V[2][2] * V[2][2];

  const float T = S0 * M00 + S1 * M11 + dsg * S2 * M22;
  const float mse = (Sp + Sq - 2.f * T) * (1.f / (3.f * (float)N_));
  return sqrtf(mse + 1e-8f);
}

__global__ __launch_bounds__(256) void kabsch_fused(
    const float* __restrict__ preds, const float* __restrict__ target,
    unsigned int* __restrict__ cnt, float* __restrict__ rm,
    float* __restrict__ out) {
  const int idx = blockIdx.x;         // 0..1279, idx = k*256 + b
  const int b = idx & 255;
  const int k = idx >> 8;
  const int pair_orig = b * K_ + k;   // preds memory order is [B,K,N,3]
  const int tid = threadIdx.x;

  const float4* __restrict__ P4 =
      reinterpret_cast<const float4*>(preds) + (size_t)pair_orig * (N_ * 3 / 4);
  const float4* __restrict__ Q4 =
      reinterpret_cast<const float4*>(target) + (size_t)b * (N_ * 3 / 4);

  float acc[NMOM];
#pragma unroll
  for (int i = 0; i < NMOM; ++i) acc[i] = 0.f;

  // 4096 points = 1024 chunks of 4 points (3 float4 each); 256 threads x 4 chunks
#pragma unroll
  for (int j = 0; j < 4; ++j) {
    const int c = tid + j * 256;
    const float4 a0 = P4[3 * c + 0], a1 = P4[3 * c + 1], a2 = P4[3 * c + 2];
    const float4 b0 = Q4[3 * c + 0], b1 = Q4[3 * c + 1], b2 = Q4[3 * c + 2];
    const float p[4][3] = {{a0.x, a0.y, a0.z},
                           {a0.w, a1.x, a1.y},
                           {a1.z, a1.w, a2.x},
                           {a2.y, a2.z, a2.w}};
    const float q[4][3] = {{b0.x, b0.y, b0.z},
                           {b0.w, b1.x, b1.y},
                           {b1.z, b1.w, b2.x},
                           {b2.y, b2.z, b2.w}};
#pragma unroll
    for (int m = 0; m < 4; ++m) {
      const float px = p[m][0], py = p[m][1], pz = p[m][2];
      const float qx = q[m][0], qy = q[m][1], qz = q[m][2];
      acc[0] += px; acc[1] += py; acc[2] += pz;
      acc[3] += qx; acc[4] += qy; acc[5] += qz;
      acc[6] = fmaf(px, px, fmaf(py, py, fmaf(pz, pz, acc[6])));
      acc[7] = fmaf(qx, qx, fmaf(qy, qy, fmaf(qz, qz, acc[7])));
      acc[8]  = fmaf(px, qx, acc[8]);
      acc[9]  = fmaf(px, qy, acc[9]);
      acc[10] = fmaf(px, qz, acc[10]);
      acc[11] = fmaf(py, qx, acc[11]);
      acc[12] = fmaf(py, qy, acc[12]);
      acc[13] = fmaf(py, qz, acc[13]);
      acc[14] = fmaf(pz, qx, acc[14]);
      acc[15] = fmaf(pz, qy, acc[15]);
      acc[16] = fmaf(pz, qz, acc[16]);
    }
  }

  // wave64 butterfly reduce, then cross-wave via LDS
#pragma unroll
  for (int off = 32; off > 0; off >>= 1) {
#pragma unroll
    for (int i = 0; i < NMOM; ++i) acc[i] += __shfl_down(acc[i], off, 64);
  }

  __shared__ float red[4][NMOM];
  __shared__ unsigned int s_done;
  const int lane = tid & 63, wid = tid >> 6;
  if (lane == 0) {
#pragma unroll
    for (int i = 0; i < NMOM; ++i) red[wid][i] = acc[i];
  }
  __syncthreads();

  // --- phase 2: one lane does the 3x3 eigensolve + rmsd, publishes it ---
  if (tid == 0) {
    float m[NMOM];
#pragma unroll
    for (int i = 0; i < NMOM; ++i)
      m[i] = red[0][i] + red[1][i] + red[2][i] + red[3][i];
    const float r = svd_rmsd(m);
    // sc1-coherent (cross-XCD visible) store, no cache maintenance:
    __hip_atomic_store(rm + idx, r, __ATOMIC_RELAXED, __HIP_MEMORY_SCOPE_AGENT);
    // Ensure the rm store is ack'd at the coherence point before the counter
    // bump can be observed (cheap per-wave wait; replaces RELEASE's wbl2):
    asm volatile("s_waitcnt vmcnt(0)" ::: "memory");
    // RELAXED: plain global_atomic_add, no buffer_wbl2 / buffer_inv.
    const unsigned int old = __hip_atomic_fetch_add(
        cnt, 1u, __ATOMIC_RELAXED, __HIP_MEMORY_SCOPE_AGENT);
    s_done = (old == (unsigned int)(NPAIR - 1)) ? 1u : 0u;
  }
  __syncthreads();

  // --- phase 3: last block reduces min-over-k, mean-over-b ---
  if (s_done) {
    const int bb = tid;  // 256 threads == B_
    float mn = __hip_atomic_load(rm + bb, __ATOMIC_RELAXED,
                                 __HIP_MEMORY_SCOPE_AGENT);
#pragma unroll
    for (int kk = 1; kk < K_; ++kk) {
      const float v = __hip_atomic_load(rm + kk * 256 + bb, __ATOMIC_RELAXED,
                                        __HIP_MEMORY_SCOPE_AGENT);
      mn = fminf(mn, v);
    }
#pragma unroll
    for (int off = 32; off > 0; off >>= 1) mn += __shfl_down(mn, off, 64);
    __shared__ float s[4];
    if ((tid & 63) == 0) s[tid >> 6] = mn;
    __syncthreads();
    if (tid == 0) out[0] = (s[0] + s[1] + s[2] + s[3]) * (1.0f / 256.0f);
  }
}

extern "C" void kernel_launch(void* const* d_in, const int* in_sizes, int n_in,
                              void* d_out, int out_size, void* d_ws, size_t ws_size,
                              hipStream_t stream) {
  const float* preds = (const float*)d_in[0];
  const float* target = (const float*)d_in[1];
  float* out = (float*)d_out;
  unsigned int* cnt = (unsigned int*)d_ws;          // 1 uint at offset 0
  float* rm = (float*)d_ws + 4;                      // NPAIR floats at +16B

  // Counter must be 0 at kernel start (ws is poisoned 0xAA once, never
  // re-poisoned; kernel leaves it at NPAIR). Graph-capturable memset node.
  hipMemsetAsync(d_ws, 0, 4, stream);
  hipLaunchKernelGGL(kabsch_fused, dim3(NPAIR), dim3(256), 0, stream,
                     preds, target, cnt, rm, out);
}

// Round 7
// 23.524 us; speedup vs baseline: 2.5635x; 1.5520x over previous
//
#include <hip/hip_runtime.h>
#include <math.h>

#define B_    256
#define K_    5
#define N_    4096
#define NPAIR (B_ * K_)     // 1280
#define NMOM  17

// ---------------------------------------------------------------------------
// Kernel 1: per-(b,k) moment reduction over N=4096 points (memory-bound).
// Block index idx = k*256 + b: all K=5 blocks sharing target slice b land on
// the same XCD (idx%8 == b%8) -> target re-reads are L2-local; unique HBM
// traffic 75.5 MB. Register double-buffer: next chunk's 6 float4 loads are
// issued before accumulating the current chunk (12 loads in flight/thread).
// Outputs 17 floats per pair: sumP[3], sumQ[3], sum|p|^2, sum|q|^2, H_raw[9].
// ---------------------------------------------------------------------------
__global__ __launch_bounds__(256) void kabsch_moments(
    const float* __restrict__ preds, const float* __restrict__ target,
    float* __restrict__ mout) {
  const int idx = blockIdx.x;         // 0..1279, idx = k*256 + b
  const int b = idx & 255;
  const int k = idx >> 8;
  const int pair_orig = b * K_ + k;   // preds memory order is [B,K,N,3]
  const int tid = threadIdx.x;

  const float4* __restrict__ P4 =
      reinterpret_cast<const float4*>(preds) + (size_t)pair_orig * (N_ * 3 / 4);
  const float4* __restrict__ Q4 =
      reinterpret_cast<const float4*>(target) + (size_t)b * (N_ * 3 / 4);

  float acc[NMOM];
#pragma unroll
  for (int i = 0; i < NMOM; ++i) acc[i] = 0.f;

  // current chunk registers (chunk = 4 points = 3 float4 from each stream)
  float4 ca0 = P4[3 * tid + 0], ca1 = P4[3 * tid + 1], ca2 = P4[3 * tid + 2];
  float4 cb0 = Q4[3 * tid + 0], cb1 = Q4[3 * tid + 1], cb2 = Q4[3 * tid + 2];

#pragma unroll
  for (int j = 0; j < 4; ++j) {
    float4 na0, na1, na2, nb0, nb1, nb2;
    if (j < 3) {  // compile-time under full unroll: prefetch next chunk
      const int c = tid + (j + 1) * 256;
      na0 = P4[3 * c + 0]; na1 = P4[3 * c + 1]; na2 = P4[3 * c + 2];
      nb0 = Q4[3 * c + 0]; nb1 = Q4[3 * c + 1]; nb2 = Q4[3 * c + 2];
    }
    const float p[4][3] = {{ca0.x, ca0.y, ca0.z},
                           {ca0.w, ca1.x, ca1.y},
                           {ca1.z, ca1.w, ca2.x},
                           {ca2.y, ca2.z, ca2.w}};
    const float q[4][3] = {{cb0.x, cb0.y, cb0.z},
                           {cb0.w, cb1.x, cb1.y},
                           {cb1.z, cb1.w, cb2.x},
                           {cb2.y, cb2.z, cb2.w}};
#pragma unroll
    for (int m = 0; m < 4; ++m) {
      const float px = p[m][0], py = p[m][1], pz = p[m][2];
      const float qx = q[m][0], qy = q[m][1], qz = q[m][2];
      acc[0] += px; acc[1] += py; acc[2] += pz;
      acc[3] += qx; acc[4] += qy; acc[5] += qz;
      acc[6] = fmaf(px, px, fmaf(py, py, fmaf(pz, pz, acc[6])));
      acc[7] = fmaf(qx, qx, fmaf(qy, qy, fmaf(qz, qz, acc[7])));
      acc[8]  = fmaf(px, qx, acc[8]);
      acc[9]  = fmaf(px, qy, acc[9]);
      acc[10] = fmaf(px, qz, acc[10]);
      acc[11] = fmaf(py, qx, acc[11]);
      acc[12] = fmaf(py, qy, acc[12]);
      acc[13] = fmaf(py, qz, acc[13]);
      acc[14] = fmaf(pz, qx, acc[14]);
      acc[15] = fmaf(pz, qy, acc[15]);
      acc[16] = fmaf(pz, qz, acc[16]);
    }
    if (j < 3) {
      ca0 = na0; ca1 = na1; ca2 = na2;
      cb0 = nb0; cb1 = nb1; cb2 = nb2;
    }
  }

  // wave64 butterfly reduce, then cross-wave via LDS
#pragma unroll
  for (int off = 32; off > 0; off >>= 1) {
#pragma unroll
    for (int i = 0; i < NMOM; ++i) acc[i] += __shfl_down(acc[i], off, 64);
  }

  __shared__ float red[4][NMOM];
  const int lane = tid & 63, wid = tid >> 6;
  if (lane == 0) {
#pragma unroll
    for (int i = 0; i < NMOM; ++i) red[wid][i] = acc[i];
  }
  __syncthreads();
  if (tid < NMOM) {
    mout[(size_t)idx * NMOM + tid] =
        red[0][tid] + red[1][tid] + red[2][tid] + red[3][tid];
  }
}

// ---------------------------------------------------------------------------
// Kernel 2: per-pair 3x3 "SVD" (f32 eigendecomposition of H^T H) + rmsd.
// Reproduces the reference's buggy R = Vh diag(1,1,d) U^T via
//   tr(H R) = S0*M00 + S1*M11 + d*S2*M22,  M = Vh*Vh, d = sign(det H).
// f32 validated end-to-end in R6 (absmax 0.0). 1280 fully-parallel chains.
// ---------------------------------------------------------------------------
__device__ inline void cross3f(const float* a, const float* b, float* c) {
  c[0] = a[1] * b[2] - a[2] * b[1];
  c[1] = a[2] * b[0] - a[0] * b[2];
  c[2] = a[0] * b[1] - a[1] * b[0];
}
__device__ inline float dot3f(const float* a, const float* b) {
  return a[0] * b[0] + a[1] * b[1] + a[2] * b[2];
}
__device__ inline void fixsign3f(float* v) {
  const float a0 = fabsf(v[0]), a1 = fabsf(v[1]), a2 = fabsf(v[2]);
  const int i = (a0 >= a1 && a0 >= a2) ? 0 : ((a1 >= a2) ? 1 : 2);
  if (v[i] < 0.f) { v[0] = -v[0]; v[1] = -v[1]; v[2] = -v[2]; }
}
__device__ inline void eigvec3f(const float A[3][3], float lam, float* v) {
  const float r0[3] = {A[0][0] - lam, A[0][1], A[0][2]};
  const float r1[3] = {A[1][0], A[1][1] - lam, A[1][2]};
  const float r2[3] = {A[2][0], A[2][1], A[2][2] - lam};
  float c01[3], c02[3], c12[3];
  cross3f(r0, r1, c01); cross3f(r0, r2, c02); cross3f(r1, r2, c12);
  const float n01 = dot3f(c01, c01), n02 = dot3f(c02, c02), n12 = dot3f(c12, c12);
  const float* best = c01; float nb = n01;
  if (n02 > nb) { best = c02; nb = n02; }
  if (n12 > nb) { best = c12; nb = n12; }
  if (nb < 1e-30f) { v[0] = 1.f; v[1] = 0.f; v[2] = 0.f; return; }
  const float inv = 1.f / sqrtf(nb);
  v[0] = best[0] * inv; v[1] = best[1] * inv; v[2] = best[2] * inv;
}

__global__ __launch_bounds__(256) void kabsch_svd(
    const float* __restrict__ mo, float* __restrict__ rmsd) {
  const int idx = blockIdx.x * blockDim.x + threadIdx.x;
  if (idx >= NPAIR) return;
  const float* m = mo + (size_t)idx * NMOM;
  const float invN = 1.f / (float)N_;

  const float sP[3] = {m[0], m[1], m[2]};
  const float sQ[3] = {m[3], m[4], m[5]};
  float H[3][3];
#pragma unroll
  for (int i = 0; i < 3; ++i)
#pragma unroll
    for (int j = 0; j < 3; ++j)
      H[i][j] = m[8 + 3 * i + j] - sP[i] * sQ[j] * invN;

  const float Sp = m[6] - dot3f(sP, sP) * invN;
  const float Sq = m[7] - dot3f(sQ, sQ) * invN;

  // A = H^T H (symmetric PSD)
  float A[3][3];
#pragma unroll
  for (int i = 0; i < 3; ++i)
#pragma unroll
    for (int j = 0; j < 3; ++j)
      A[i][j] = H[0][i] * H[0][j] + H[1][i] * H[1][j] + H[2][i] * H[2][j];

  float lam[3];
  float V[3][3];  // columns = eigenvectors
  const float q = (A[0][0] + A[1][1] + A[2][2]) * (1.f / 3.f);
  const float p1 = A[0][1] * A[0][1] + A[0][2] * A[0][2] + A[1][2] * A[1][2];
  const float p2 = (A[0][0] - q) * (A[0][0] - q) +
                   (A[1][1] - q) * (A[1][1] - q) +
                   (A[2][2] - q) * (A[2][2] - q) + 2.f * p1;
  if (p2 < 1e-20f) {
    lam[0] = lam[1] = lam[2] = q;
#pragma unroll
    for (int i = 0; i < 3; ++i)
#pragma unroll
      for (int j = 0; j < 3; ++j) V[i][j] = (i == j) ? 1.f : 0.f;
  } else {
    const float p = sqrtf(p2 * (1.f / 6.f));
    const float invp = 1.f / p;
    float Bm[3][3];
#pragma unroll
    for (int i = 0; i < 3; ++i)
#pragma unroll
      for (int j = 0; j < 3; ++j)
        Bm[i][j] = (A[i][j] - ((i == j) ? q : 0.f)) * invp;
    const float detB =
        Bm[0][0] * (Bm[1][1] * Bm[2][2] - Bm[1][2] * Bm[2][1]) -
        Bm[0][1] * (Bm[1][0] * Bm[2][2] - Bm[1][2] * Bm[2][0]) +
        Bm[0][2] * (Bm[1][0] * Bm[2][1] - Bm[1][1] * Bm[2][0]);
    float r = detB * 0.5f;
    r = fminf(1.f, fmaxf(-1.f, r));
    const float phi = acosf(r) * (1.f / 3.f);
    lam[0] = q + 2.f * p * cosf(phi);
    lam[2] = q + 2.f * p * cosf(phi + 2.0943951023931953f);  // +2pi/3
    lam[1] = 3.f * q - lam[0] - lam[2];

    float v1[3], v2[3], v3[3];
    eigvec3f(A, lam[0], v1);
    eigvec3f(A, lam[1], v2);
    // orthogonalize v2 against v1
    const float d12 = dot3f(v1, v2);
    v2[0] -= d12 * v1[0]; v2[1] -= d12 * v1[1]; v2[2] -= d12 * v1[2];
    float n2 = dot3f(v2, v2);
    if (n2 < 1e-12f) {
      const float a0 = fabsf(v1[0]), a1f = fabsf(v1[1]), a2f = fabsf(v1[2]);
      int ax = (a0 <= a1f && a0 <= a2f) ? 0 : ((a1f <= a2f) ? 1 : 2);
      float e[3] = {0.f, 0.f, 0.f};
      e[ax] = 1.f;
      const float de = dot3f(v1, e);
      v2[0] = e[0] - de * v1[0]; v2[1] = e[1] - de * v1[1]; v2[2] = e[2] - de * v1[2];
      n2 = dot3f(v2, v2);
    }
    const float invn2 = 1.f / sqrtf(n2);
    v2[0] *= invn2; v2[1] *= invn2; v2[2] *= invn2;

    fixsign3f(v1);
    fixsign3f(v2);
    cross3f(v1, v2, v3);
#pragma unroll
    for (int i = 0; i < 3; ++i) { V[i][0] = v1[i]; V[i][1] = v2[i]; V[i][2] = v3[i]; }
  }

  const float S0 = sqrtf(fmaxf(lam[0], 0.f));
  const float S1 = sqrtf(fmaxf(lam[1], 0.f));
  const float S2 = sqrtf(fmaxf(lam[2], 0.f));

  const float detH =
      H[0][0] * (H[1][1] * H[2][2] - H[1][2] * H[2][1]) -
      H[0][1] * (H[1][0] * H[2][2] - H[1][2] * H[2][0]) +
      H[0][2] * (H[1][0] * H[2][1] - H[1][1] * H[2][0]);
  const float dsg = (detH >= 0.f) ? 1.f : -1.f;

  // M = Vh*Vh (Vh = V^T): M_ii = sum_k V[k][i] * V[i][k]
  const float M00 = V[0][0] * V[0][0] + V[1][0] * V[0][1] + V[2][0] * V[0][2];
  const float M11 = V[0][1] * V[1][0] + V[1][1] * V[1][1] + V[2][1] * V[1][2];
  const float M22 = V[0][2] * V[2][0] + V[1][2] * V[2][1] + V[2][2] * V[2][2];

  const float T = S0 * M00 + S1 * M11 + dsg * S2 * M22;
  const float mse = (Sp + Sq - 2.f * T) * (1.f / (3.f * (float)N_));
  rmsd[idx] = sqrtf(mse + 1e-8f);
}

// ---------------------------------------------------------------------------
// Kernel 3: min over K, mean over B -> scalar.
// rmsd layout is idx = k*256 + b, so per-b min reads stride-256 (coalesced).
// ---------------------------------------------------------------------------
__global__ __launch_bounds__(256) void kabsch_final(
    const float* __restrict__ rmsd, float* __restrict__ out) {
  const int b = threadIdx.x;  // 256 threads == B_
  float mn = rmsd[b];
#pragma unroll
  for (int k = 1; k < K_; ++k) mn = fminf(mn, rmsd[k * 256 + b]);
#pragma unroll
  for (int off = 32; off > 0; off >>= 1) mn += __shfl_down(mn, off, 64);
  __shared__ float s[4];
  if ((b & 63) == 0) s[b >> 6] = mn;
  __syncthreads();
  if (b == 0) out[0] = (s[0] + s[1] + s[2] + s[3]) * (1.0f / 256.0f);
}

extern "C" void kernel_launch(void* const* d_in, const int* in_sizes, int n_in,
                              void* d_out, int out_size, void* d_ws, size_t ws_size,
                              hipStream_t stream) {
  const float* preds = (const float*)d_in[0];
  const float* target = (const float*)d_in[1];
  float* out = (float*)d_out;
  float* mo = (float*)d_ws;                      // NPAIR*NMOM floats
  float* rm = mo + (size_t)NPAIR * NMOM;         // NPAIR floats

  hipLaunchKernelGGL(kabsch_moments, dim3(NPAIR), dim3(256), 0, stream,
                     preds, target, mo);
  hipLaunchKernelGGL(kabsch_svd, dim3((NPAIR + 255) / 256), dim3(256), 0, stream,
                     mo, rm);
  hipLaunchKernelGGL(kabsch_final, dim3(1), dim3(256), 0, stream, rm, out);
}

// Round 8
// 22.101 us; speedup vs baseline: 2.7285x; 1.0644x over previous
//
#include <hip/hip_runtime.h>
#include <math.h>

#define B_    256
#define K_    5
#define N_    4096
#define NPAIR (B_ * K_)     // 1280
#define NMOM  17

// ---------------------------------------------------------------------------
// f32 3x3 eigensolve helpers (validated end-to-end: absmax 0.0 in R6/R7).
// ---------------------------------------------------------------------------
__device__ inline void cross3f(const float* a, const float* b, float* c) {
  c[0] = a[1] * b[2] - a[2] * b[1];
  c[1] = a[2] * b[0] - a[0] * b[2];
  c[2] = a[0] * b[1] - a[1] * b[0];
}
__device__ inline float dot3f(const float* a, const float* b) {
  return a[0] * b[0] + a[1] * b[1] + a[2] * b[2];
}
__device__ inline void fixsign3f(float* v) {
  const float a0 = fabsf(v[0]), a1 = fabsf(v[1]), a2 = fabsf(v[2]);
  const int i = (a0 >= a1 && a0 >= a2) ? 0 : ((a1 >= a2) ? 1 : 2);
  if (v[i] < 0.f) { v[0] = -v[0]; v[1] = -v[1]; v[2] = -v[2]; }
}
__device__ inline void eigvec3f(const float A[3][3], float lam, float* v) {
  const float r0[3] = {A[0][0] - lam, A[0][1], A[0][2]};
  const float r1[3] = {A[1][0], A[1][1] - lam, A[1][2]};
  const float r2[3] = {A[2][0], A[2][1], A[2][2] - lam};
  float c01[3], c02[3], c12[3];
  cross3f(r0, r1, c01); cross3f(r0, r2, c02); cross3f(r1, r2, c12);
  const float n01 = dot3f(c01, c01), n02 = dot3f(c02, c02), n12 = dot3f(c12, c12);
  const float* best = c01; float nb = n01;
  if (n02 > nb) { best = c02; nb = n02; }
  if (n12 > nb) { best = c12; nb = n12; }
  if (nb < 1e-30f) { v[0] = 1.f; v[1] = 0.f; v[2] = 0.f; return; }
  const float inv = 1.f / sqrtf(nb);
  v[0] = best[0] * inv; v[1] = best[1] * inv; v[2] = best[2] * inv;
}

// Reproduces the reference's buggy R = Vh diag(1,1,d) U^T via
//   tr(H R) = S0*M00 + S1*M11 + d*S2*M22,  M = Vh*Vh, d = sign(det H).
__device__ inline float svd_rmsd(const float* m) {
  const float invN = 1.f / (float)N_;
  const float sP[3] = {m[0], m[1], m[2]};
  const float sQ[3] = {m[3], m[4], m[5]};
  float H[3][3];
#pragma unroll
  for (int i = 0; i < 3; ++i)
#pragma unroll
    for (int j = 0; j < 3; ++j)
      H[i][j] = m[8 + 3 * i + j] - sP[i] * sQ[j] * invN;

  const float Sp = m[6] - dot3f(sP, sP) * invN;
  const float Sq = m[7] - dot3f(sQ, sQ) * invN;

  // A = H^T H (symmetric PSD)
  float A[3][3];
#pragma unroll
  for (int i = 0; i < 3; ++i)
#pragma unroll
    for (int j = 0; j < 3; ++j)
      A[i][j] = H[0][i] * H[0][j] + H[1][i] * H[1][j] + H[2][i] * H[2][j];

  float lam[3];
  float V[3][3];  // columns = eigenvectors
  const float q = (A[0][0] + A[1][1] + A[2][2]) * (1.f / 3.f);
  const float p1 = A[0][1] * A[0][1] + A[0][2] * A[0][2] + A[1][2] * A[1][2];
  const float p2 = (A[0][0] - q) * (A[0][0] - q) +
                   (A[1][1] - q) * (A[1][1] - q) +
                   (A[2][2] - q) * (A[2][2] - q) + 2.f * p1;
  if (p2 < 1e-20f) {
    lam[0] = lam[1] = lam[2] = q;
#pragma unroll
    for (int i = 0; i < 3; ++i)
#pragma unroll
      for (int j = 0; j < 3; ++j) V[i][j] = (i == j) ? 1.f : 0.f;
  } else {
    const float p = sqrtf(p2 * (1.f / 6.f));
    const float invp = 1.f / p;
    float Bm[3][3];
#pragma unroll
    for (int i = 0; i < 3; ++i)
#pragma unroll
      for (int j = 0; j < 3; ++j)
        Bm[i][j] = (A[i][j] - ((i == j) ? q : 0.f)) * invp;
    const float detB =
        Bm[0][0] * (Bm[1][1] * Bm[2][2] - Bm[1][2] * Bm[2][1]) -
        Bm[0][1] * (Bm[1][0] * Bm[2][2] - Bm[1][2] * Bm[2][0]) +
        Bm[0][2] * (Bm[1][0] * Bm[2][1] - Bm[1][1] * Bm[2][0]);
    float r = detB * 0.5f;
    r = fminf(1.f, fmaxf(-1.f, r));
    const float phi = acosf(r) * (1.f / 3.f);
    lam[0] = q + 2.f * p * cosf(phi);
    lam[2] = q + 2.f * p * cosf(phi + 2.0943951023931953f);  // +2pi/3
    lam[1] = 3.f * q - lam[0] - lam[2];

    float v1[3], v2[3], v3[3];
    eigvec3f(A, lam[0], v1);
    eigvec3f(A, lam[1], v2);
    // orthogonalize v2 against v1
    const float d12 = dot3f(v1, v2);
    v2[0] -= d12 * v1[0]; v2[1] -= d12 * v1[1]; v2[2] -= d12 * v1[2];
    float n2 = dot3f(v2, v2);
    if (n2 < 1e-12f) {
      const float a0 = fabsf(v1[0]), a1f = fabsf(v1[1]), a2f = fabsf(v1[2]);
      int ax = (a0 <= a1f && a0 <= a2f) ? 0 : ((a1f <= a2f) ? 1 : 2);
      float e[3] = {0.f, 0.f, 0.f};
      e[ax] = 1.f;
      const float de = dot3f(v1, e);
      v2[0] = e[0] - de * v1[0]; v2[1] = e[1] - de * v1[1]; v2[2] = e[2] - de * v1[2];
      n2 = dot3f(v2, v2);
    }
    const float invn2 = 1.f / sqrtf(n2);
    v2[0] *= invn2; v2[1] *= invn2; v2[2] *= invn2;

    fixsign3f(v1);
    fixsign3f(v2);
    cross3f(v1, v2, v3);
#pragma unroll
    for (int i = 0; i < 3; ++i) { V[i][0] = v1[i]; V[i][1] = v2[i]; V[i][2] = v3[i]; }
  }

  const float S0 = sqrtf(fmaxf(lam[0], 0.f));
  const float S1 = sqrtf(fmaxf(lam[1], 0.f));
  const float S2 = sqrtf(fmaxf(lam[2], 0.f));

  const float detH =
      H[0][0] * (H[1][1] * H[2][2] - H[1][2] * H[2][1]) -
      H[0][1] * (H[1][0] * H[2][2] - H[1][2] * H[2][0]) +
      H[0][2] * (H[1][0] * H[2][1] - H[1][1] * H[2][0]);
  const float dsg = (detH >= 0.f) ? 1.f : -1.f;

  // M = Vh*Vh (Vh = V^T): M_ii = sum_k V[k][i] * V[i][k]
  const float M00 = V[0][0] * V[0][0] + V[1][0] * V[0][1] + V[2][0] * V[0][2];
  const float M11 = V[0][1] * V[1][0] + V[1][1] * V[1][1] + V[2][1] * V[1][2];
  const float M22 = V[0][2] * V[2][0] + V[1][2] * V[2][1] + V[2][2] * V[2][2];

  const float T = S0 * M00 + S1 * M11 + dsg * S2 * M22;
  const float mse = (Sp + Sq - 2.f * T) * (1.f / (3.f * (float)N_));
  return sqrtf(mse + 1e-8f);
}

// ---------------------------------------------------------------------------
// Kernel 1: per-(b,k) moments + in-block svd -> rmsd[idx], plain store.
// No cross-block sync of any kind (the R4/R6 failure modes: acq-rel L2
// flush/inv storms, single-counter RMW serialization, vmcnt store-ack holds
// -- all absent here). Block index idx = k*256 + b keeps all K=5 blocks of a
// given b on one XCD (idx%8 == b%8) for L2-local target re-reads.
// ---------------------------------------------------------------------------
__global__ __launch_bounds__(256) void kabsch_moments_svd(
    const float* __restrict__ preds, const float* __restrict__ target,
    float* __restrict__ rmsd) {
  const int idx = blockIdx.x;         // 0..1279, idx = k*256 + b
  const int b = idx & 255;
  const int k = idx >> 8;
  const int pair_orig = b * K_ + k;   // preds memory order is [B,K,N,3]
  const int tid = threadIdx.x;

  const float4* __restrict__ P4 =
      reinterpret_cast<const float4*>(preds) + (size_t)pair_orig * (N_ * 3 / 4);
  const float4* __restrict__ Q4 =
      reinterpret_cast<const float4*>(target) + (size_t)b * (N_ * 3 / 4);

  float acc[NMOM];
#pragma unroll
  for (int i = 0; i < NMOM; ++i) acc[i] = 0.f;

  // 4096 points = 1024 chunks of 4 points (3 float4 each); 256 threads x 4
#pragma unroll
  for (int j = 0; j < 4; ++j) {
    const int c = tid + j * 256;
    const float4 a0 = P4[3 * c + 0], a1 = P4[3 * c + 1], a2 = P4[3 * c + 2];
    const float4 b0 = Q4[3 * c + 0], b1 = Q4[3 * c + 1], b2 = Q4[3 * c + 2];
    const float p[4][3] = {{a0.x, a0.y, a0.z},
                           {a0.w, a1.x, a1.y},
                           {a1.z, a1.w, a2.x},
                           {a2.y, a2.z, a2.w}};
    const float q[4][3] = {{b0.x, b0.y, b0.z},
                           {b0.w, b1.x, b1.y},
                           {b1.z, b1.w, b2.x},
                           {b2.y, b2.z, b2.w}};
#pragma unroll
    for (int m = 0; m < 4; ++m) {
      const float px = p[m][0], py = p[m][1], pz = p[m][2];
      const float qx = q[m][0], qy = q[m][1], qz = q[m][2];
      acc[0] += px; acc[1] += py; acc[2] += pz;
      acc[3] += qx; acc[4] += qy; acc[5] += qz;
      acc[6] = fmaf(px, px, fmaf(py, py, fmaf(pz, pz, acc[6])));
      acc[7] = fmaf(qx, qx, fmaf(qy, qy, fmaf(qz, qz, acc[7])));
      acc[8]  = fmaf(px, qx, acc[8]);
      acc[9]  = fmaf(px, qy, acc[9]);
      acc[10] = fmaf(px, qz, acc[10]);
      acc[11] = fmaf(py, qx, acc[11]);
      acc[12] = fmaf(py, qy, acc[12]);
      acc[13] = fmaf(py, qz, acc[13]);
      acc[14] = fmaf(pz, qx, acc[14]);
      acc[15] = fmaf(pz, qy, acc[15]);
      acc[16] = fmaf(pz, qz, acc[16]);
    }
  }

  // wave64 butterfly reduce, then cross-wave via LDS
#pragma unroll
  for (int off = 32; off > 0; off >>= 1) {
#pragma unroll
    for (int i = 0; i < NMOM; ++i) acc[i] += __shfl_down(acc[i], off, 64);
  }

  __shared__ float red[4][NMOM];
  const int lane = tid & 63, wid = tid >> 6;
  if (lane == 0) {
#pragma unroll
    for (int i = 0; i < NMOM; ++i) red[wid][i] = acc[i];
  }
  __syncthreads();

  // in-block svd tail: ~1.5k-cycle f32 chain on lane 0, plain store, done.
  if (tid == 0) {
    float m[NMOM];
#pragma unroll
    for (int i = 0; i < NMOM; ++i)
      m[i] = red[0][i] + red[1][i] + red[2][i] + red[3][i];
    rmsd[idx] = svd_rmsd(m);
  }
}

// ---------------------------------------------------------------------------
// Kernel 2: min over K, mean over B -> scalar.
// rmsd layout is idx = k*256 + b, so per-b min reads stride-256 (coalesced).
// ---------------------------------------------------------------------------
__global__ __launch_bounds__(256) void kabsch_final(
    const float* __restrict__ rmsd, float* __restrict__ out) {
  const int b = threadIdx.x;  // 256 threads == B_
  float mn = rmsd[b];
#pragma unroll
  for (int k = 1; k < K_; ++k) mn = fminf(mn, rmsd[k * 256 + b]);
#pragma unroll
  for (int off = 32; off > 0; off >>= 1) mn += __shfl_down(mn, off, 64);
  __shared__ float s[4];
  if ((b & 63) == 0) s[b >> 6] = mn;
  __syncthreads();
  if (b == 0) out[0] = (s[0] + s[1] + s[2] + s[3]) * (1.0f / 256.0f);
}

extern "C" void kernel_launch(void* const* d_in, const int* in_sizes, int n_in,
                              void* d_out, int out_size, void* d_ws, size_t ws_size,
                              hipStream_t stream) {
  const float* preds = (const float*)d_in[0];
  const float* target = (const float*)d_in[1];
  float* out = (float*)d_out;
  float* rm = (float*)d_ws;                      // NPAIR floats

  hipLaunchKernelGGL(kabsch_moments_svd, dim3(NPAIR), dim3(256), 0, stream,
                     preds, target, rm);
  hipLaunchKernelGGL(kabsch_final, dim3(1), dim3(256), 0, stream, rm, out);
}